// Round 6
// baseline (165.326 us; speedup 1.0000x reference)
//
#include <hip/hip_runtime.h>

#define L 200
#define D 64
#define DA 128
#define INV_SCALE 0.088388347648318440550f  // 1/sqrt(128)

typedef float f32x4 __attribute__((ext_vector_type(4)));
typedef float f32x2 __attribute__((ext_vector_type(2)));
typedef int   i32x4 __attribute__((ext_vector_type(4)));

// One fused kernel, one wave per batch row, NO __syncthreads (all LDS is
// per-wave private), no workspace, no prep kernel.
//   z  = t @ Wq                     (readlane broadcast + coalesced f32x2)
//   q~ = (z @ Wk^T)/sqrt(128)       (32 coalesced Wk chunks + butterfly)
//   stream hist (nontemporal), relu(mask*score), accumulate c in registers
//   u  = c @ Wv ; out = u @ Wo + t  (static shfls + coalesced weight loads)
__global__ __launch_bounds__(256, 6) void attn_fused(
    const float* __restrict__ target, const float* __restrict__ hist,
    const int* __restrict__ mask,
    const float* __restrict__ Wq, const float* __restrict__ Wk,
    const float* __restrict__ Wv, const float* __restrict__ Wo,
    float* __restrict__ out)
{
    __shared__ float smask[4][L];   // per-wave mask row (floats)
    __shared__ float qs[4][D];      // per-wave q~ buffer

    const int tid  = threadIdx.x;
    const int wave = tid >> 6, lane = tid & 63;
    const int b    = blockIdx.x * 4 + wave;
    const float* __restrict__ hb = hist + (size_t)b * (L * D);
    const int lr = lane >> 4;

    const float t = target[b * D + lane];

    // mask row -> per-wave LDS (0/1 as float); same-wave RAW, no barrier
    if (lane < 50) {
        i32x4 mv = *(const i32x4*)(mask + b * L + lane * 4);
        f32x4 mf = { (float)mv.x, (float)mv.y, (float)mv.z, (float)mv.w };
        *(f32x4*)&smask[wave][lane * 4] = mf;
    }

    // prefetch hist chunks 0,1 (rows 0..31, 8KB/wave) — consumed after prologue
    const float* hp = hb + lane * 4;
    #define NT(off) __builtin_nontemporal_load((const f32x4*)(hp + (off)))
    f32x4 A0 = NT(0),    A1 = NT(256),  A2 = NT(512),  A3 = NT(768);
    f32x4 B0 = NT(1024), B1 = NT(1280), B2 = NT(1536), B3 = NT(1792);

    // z_a = sum_i t_i * Wq[i,a]; layout: z0 = z[2*lane], z1 = z[2*lane+1]
    float z0 = 0.f, z1 = 0.f;
    #pragma unroll
    for (int i = 0; i < D; ++i) {
        float ti = __shfl(t, i);                       // readlane
        f32x2 wq = *(const f32x2*)(Wq + i * DA + lane * 2);
        z0 = fmaf(ti, wq.x, z0);
        z1 = fmaf(ti, wq.y, z1);
    }

    // q~_r = sum_a z_a * Wk[r,a]; chunk c covers rows 2c,2c+1 fully
    #pragma unroll
    for (int c = 0; c < 32; ++c) {
        f32x4 w = *(const f32x4*)(Wk + c * 256 + lane * 4);
        const int m = lane & 31;                       // col group: a0 = 4m
        float za0 = __shfl(z0, 2 * m);                 // z[4m]
        float za1 = __shfl(z1, 2 * m);                 // z[4m+1]
        float za2 = __shfl(z0, 2 * m + 1);             // z[4m+2]
        float za3 = __shfl(z1, 2 * m + 1);             // z[4m+3]
        float p = w.x * za0 + w.y * za1 + w.z * za2 + w.w * za3;
        p += __shfl_xor(p, 1);
        p += __shfl_xor(p, 2);
        p += __shfl_xor(p, 4);
        p += __shfl_xor(p, 8);
        p += __shfl_xor(p, 16);                        // 32-lane halves reduced
        if ((lane & 31) == 0) qs[wave][2 * c + (lane >> 5)] = p;
    }

    // redistribute: lane needs q~[(lane&15)*4 + k]  (same-wave LDS, no barrier)
    f32x4 q = *(const f32x4*)&qs[wave][(lane & 15) * 4];
    q *= INV_SCALE;

    f32x4 acc = { 0.f, 0.f, 0.f, 0.f };

    #define PROC(v, ROW0) {                                               \
        float s = v.x * q.x + v.y * q.y + v.z * q.z + v.w * q.w;          \
        s += __shfl_xor(s, 1);                                            \
        s += __shfl_xor(s, 2);                                            \
        s += __shfl_xor(s, 4);                                            \
        s += __shfl_xor(s, 8);                                            \
        float mf = smask[wave][(ROW0) + lr];                              \
        float aw = fmaxf(s * mf, 0.f);                                    \
        acc += v * aw; }

    PROC(A0, 0)  PROC(A1, 4)  PROC(A2, 8)  PROC(A3, 12)
    PROC(B0, 16) PROC(B1, 20) PROC(B2, 24) PROC(B3, 28)

    #pragma unroll
    for (int cc = 2; cc < 12; ++cc) {
        f32x4 v0 = NT(cc * 1024);
        f32x4 v1 = NT(cc * 1024 + 256);
        f32x4 v2 = NT(cc * 1024 + 512);
        f32x4 v3 = NT(cc * 1024 + 768);
        PROC(v0, cc * 16)      PROC(v1, cc * 16 + 4)
        PROC(v2, cc * 16 + 8)  PROC(v3, cc * 16 + 12)
    }
    {   // tail rows 192..199
        f32x4 T0 = NT(12288), T1 = NT(12544);
        PROC(T0, 192) PROC(T1, 196)
    }
    #undef PROC
    #undef NT

    // reduce acc across the 4 lanes sharing each column group
    acc.x += __shfl_xor(acc.x, 16); acc.x += __shfl_xor(acc.x, 32);
    acc.y += __shfl_xor(acc.y, 16); acc.y += __shfl_xor(acc.y, 32);
    acc.z += __shfl_xor(acc.z, 16); acc.z += __shfl_xor(acc.z, 32);
    acc.w += __shfl_xor(acc.w, 16); acc.w += __shfl_xor(acc.w, 32);

    // u_a = sum_i c_i * Wv[i,a]; layout u0 = u[2*lane], u1 = u[2*lane+1]
    float u0 = 0.f, u1 = 0.f;
    #pragma unroll
    for (int g = 0; g < 16; ++g) {                     // c[4g .. 4g+3]
        float c0 = __shfl(acc.x, g);
        float c1 = __shfl(acc.y, g);
        float c2 = __shfl(acc.z, g);
        float c3 = __shfl(acc.w, g);
        f32x2 w0 = *(const f32x2*)(Wv + (4 * g + 0) * DA + lane * 2);
        f32x2 w1 = *(const f32x2*)(Wv + (4 * g + 1) * DA + lane * 2);
        f32x2 w2 = *(const f32x2*)(Wv + (4 * g + 2) * DA + lane * 2);
        f32x2 w3 = *(const f32x2*)(Wv + (4 * g + 3) * DA + lane * 2);
        u0 = fmaf(c0, w0.x, u0); u1 = fmaf(c0, w0.y, u1);
        u0 = fmaf(c1, w1.x, u0); u1 = fmaf(c1, w1.y, u1);
        u0 = fmaf(c2, w2.x, u0); u1 = fmaf(c2, w2.y, u1);
        u0 = fmaf(c3, w3.x, u0); u1 = fmaf(c3, w3.y, u1);
    }

    // out[b][lane] = t + sum_a u_a * Wo[a,lane]
    float o = t;
    #pragma unroll
    for (int a2 = 0; a2 < 64; ++a2) {
        float ue = __shfl(u0, a2);                     // u[2*a2]
        float uo = __shfl(u1, a2);                     // u[2*a2+1]
        o = fmaf(ue, Wo[(2 * a2) * D + lane], o);
        o = fmaf(uo, Wo[(2 * a2 + 1) * D + lane], o);
    }
    out[b * D + lane] = o;
}

extern "C" void kernel_launch(void* const* d_in, const int* in_sizes, int n_in,
                              void* d_out, int out_size, void* d_ws, size_t ws_size,
                              hipStream_t stream) {
    const float* target = (const float*)d_in[0];
    const float* hist   = (const float*)d_in[1];
    const int*   mask   = (const int*)d_in[2];
    const float* Wq     = (const float*)d_in[3];
    const float* Wk     = (const float*)d_in[4];
    const float* Wv     = (const float*)d_in[5];
    const float* Wo     = (const float*)d_in[6];
    float* outp = (float*)d_out;

    attn_fused<<<8192 / 4, 256, 0, stream>>>(target, hist, mask,
                                             Wq, Wk, Wv, Wo, outp);
}

// Round 7
// 51.100 us; speedup vs baseline: 3.2354x; 3.2354x over previous
//
#include <hip/hip_runtime.h>

#define L 200
#define D 64
#define DA 128
#define INV_SCALE 0.088388347648318440550f  // 1/sqrt(128)

typedef float f32x4 __attribute__((ext_vector_type(4)));
typedef int   i32x4 __attribute__((ext_vector_type(4)));

// ---------- prep: M = W_q @ W_k^T (64x64), P = W_v @ W_o (64x64) ----------
__global__ __launch_bounds__(256) void prep_kernel(
    const float* __restrict__ Wq, const float* __restrict__ Wk,
    const float* __restrict__ Wv, const float* __restrict__ Wo,
    float* __restrict__ MP)
{
    int gid = blockIdx.x * 256 + threadIdx.x;
    if (gid < 4096) {
        int i = gid >> 6, j = gid & 63;
        float s = 0.f;
        #pragma unroll 8
        for (int a = 0; a < DA; ++a) s += Wq[i * DA + a] * Wk[j * DA + a];
        MP[gid] = s;                       // M[i][j]
    } else if (gid < 8192) {
        int g = gid - 4096;
        int i = g >> 6, j = g & 63;
        float s = 0.f;
        #pragma unroll 8
        for (int a = 0; a < DA; ++a) s += Wv[i * DA + a] * Wo[a * D + j];
        MP[gid] = s;                       // P[i][j]
    }
}

// ---------- main: one wave per batch row; load ONLY mask!=0 history rows ----
// Active-row compaction via 4 ballot prefix-sums (deterministic, no atomics).
// Gather: 4 active rows per instruction, each row = 16 lanes x 16B = 256B
// contiguous. Rows with mask=0 are never read -> ~half the HBM traffic.
__global__ __launch_bounds__(256, 8) void attn_kernel(
    const float* __restrict__ hist, const int* __restrict__ mask,
    const float* __restrict__ target, const float* __restrict__ MP,
    float* __restrict__ out)
{
    __shared__ int   act[4][204];      // active row indices per wave
    __shared__ float c_lds[4][D];

    const int tid  = threadIdx.x;
    const int wave = tid >> 6, lane = tid & 63;
    const int b    = blockIdx.x * 4 + wave;
    const float* __restrict__ hb = hist + (size_t)b * (L * D);
    const int lr = lane >> 4;

    const float t = target[b * D + lane];

    // ---- compact active rows: lane l<50 owns mask rows 4l..4l+3 ----
    i32x4 mv = { 0, 0, 0, 0 };
    if (lane < 50) mv = *(const i32x4*)(mask + b * L + lane * 4);
    const unsigned long long below = (1ull << lane) - 1ull;
    int base = 0;
    #pragma unroll
    for (int k = 0; k < 4; ++k) {
        int mk = (k == 0) ? mv.x : (k == 1) ? mv.y : (k == 2) ? mv.z : mv.w;
        bool a_ = (lane < 50) && (mk != 0);
        unsigned long long bm = __ballot(a_);
        if (a_) act[wave][base + __popcll(bm & below)] = lane * 4 + k;
        base += __popcll(bm);
    }
    const int nA = base;
    if (lane < 3) act[wave][nA + lane] = 0;   // pad (killed by valid flag)

    const int nIt = (nA + 3) >> 2;
    const float* hbl = hb + (lane & 15) * 4;
    #define LOADROW(i) __builtin_nontemporal_load( \
        (const f32x4*)(hbl + act[wave][(i) * 4 + lr] * D))

    // prefetch first two gather chunks (hides HBM latency under q~ prologue)
    f32x4 A = { 0.f, 0.f, 0.f, 0.f }, B = { 0.f, 0.f, 0.f, 0.f };
    if (nIt > 0) A = LOADROW(0);
    if (nIt > 1) B = LOADROW(1);

    // ---- q~[lane] = INV_SCALE * sum_i t_i * M[i][lane]  (MP is L1-resident)
    float qacc = 0.f;
    #pragma unroll 8
    for (int i = 0; i < D; ++i)
        qacc = fmaf(__shfl(t, i), MP[i * D + lane], qacc);
    qacc *= INV_SCALE;
    const int qb = (lane & 15) * 4;
    f32x4 q;
    q.x = __shfl(qacc, qb + 0);
    q.y = __shfl(qacc, qb + 1);
    q.z = __shfl(qacc, qb + 2);
    q.w = __shfl(qacc, qb + 3);

    // ---- main gather loop, depth-2 pipeline ----
    f32x4 acc = { 0.f, 0.f, 0.f, 0.f };
    for (int i = 0; i < nIt; ++i) {
        f32x4 N = { 0.f, 0.f, 0.f, 0.f };
        if (i + 2 < nIt) N = LOADROW(i + 2);
        float s = A.x * q.x + A.y * q.y + A.z * q.z + A.w * q.w;
        s += __shfl_xor(s, 1);
        s += __shfl_xor(s, 2);
        s += __shfl_xor(s, 4);
        s += __shfl_xor(s, 8);
        float aw = (i * 4 + lr < nA) ? fmaxf(s, 0.f) : 0.f;
        acc += A * aw;
        A = B; B = N;
    }
    #undef LOADROW

    // reduce acc across the 4 row-groups (lanes xor 16, 32)
    acc.x += __shfl_xor(acc.x, 16); acc.x += __shfl_xor(acc.x, 32);
    acc.y += __shfl_xor(acc.y, 16); acc.y += __shfl_xor(acc.y, 32);
    acc.z += __shfl_xor(acc.z, 16); acc.z += __shfl_xor(acc.z, 32);
    acc.w += __shfl_xor(acc.w, 16); acc.w += __shfl_xor(acc.w, 32);

    if (lane < 16) *(f32x4*)&c_lds[wave][lane * 4] = acc;
    // same-wave LDS RAW: compiler orders via lgkmcnt, no barrier needed

    // ---- epilogue: out[b][lane] = t + sum_i c[i] * P[i][lane] ----
    float o = t;
    const float* __restrict__ P = MP + 4096;
    #pragma unroll 8
    for (int i = 0; i < D; ++i)
        o = fmaf(c_lds[wave][i], P[i * D + lane], o);
    out[b * D + lane] = o;
}

extern "C" void kernel_launch(void* const* d_in, const int* in_sizes, int n_in,
                              void* d_out, int out_size, void* d_ws, size_t ws_size,
                              hipStream_t stream) {
    const float* target = (const float*)d_in[0];
    const float* hist   = (const float*)d_in[1];
    const int*   mask   = (const int*)d_in[2];
    const float* Wq     = (const float*)d_in[3];
    const float* Wk     = (const float*)d_in[4];
    const float* Wv     = (const float*)d_in[5];
    const float* Wo     = (const float*)d_in[6];
    float* outp = (float*)d_out;
    float* MP   = (float*)d_ws;                 // 8192 floats: M, then P

    prep_kernel<<<32, 256, 0, stream>>>(Wq, Wk, Wv, Wo, MP);
    attn_kernel<<<8192 / 4, 256, 0, stream>>>(hist, mask, target, MP, outp);
}

// Round 8
// 50.804 us; speedup vs baseline: 3.2542x; 1.0058x over previous
//
#include <hip/hip_runtime.h>

#define L 200
#define D 64
#define DA 128
#define INV_SCALE 0.088388347648318440550f  // 1/sqrt(128)

typedef float f32x4 __attribute__((ext_vector_type(4)));
typedef int   i32x4 __attribute__((ext_vector_type(4)));

// DPP-based add: x + dpp_perm(x). CTRL: 0xB1 = quad_perm(xor1),
// 0x4E = quad_perm(xor2), 0x141 = row_half_mirror (== xor4 once quads are
// uniform), 0x140 = row_mirror (== xor8 once 8-groups are uniform).
template <int CTRL>
__device__ __forceinline__ float dpp_add(float x) {
    int xi = __builtin_bit_cast(int, x);
    int yi = __builtin_amdgcn_update_dpp(xi, xi, CTRL, 0xF, 0xF, false);
    return x + __builtin_bit_cast(float, yi);
}

// ---------- prep: M = W_q @ W_k^T (64x64), P = W_v @ W_o (64x64) ----------
__global__ __launch_bounds__(256) void prep_kernel(
    const float* __restrict__ Wq, const float* __restrict__ Wk,
    const float* __restrict__ Wv, const float* __restrict__ Wo,
    float* __restrict__ MP)
{
    int gid = blockIdx.x * 256 + threadIdx.x;
    if (gid < 4096) {
        int i = gid >> 6, j = gid & 63;
        float s = 0.f;
        #pragma unroll 8
        for (int a = 0; a < DA; ++a) s += Wq[i * DA + a] * Wk[j * DA + a];
        MP[gid] = s;                       // M[i][j]
    } else if (gid < 8192) {
        int g = gid - 4096;
        int i = g >> 6, j = g & 63;
        float s = 0.f;
        #pragma unroll 8
        for (int a = 0; a < DA; ++a) s += Wv[i * DA + a] * Wo[a * D + j];
        MP[gid] = s;                       // P[i][j]
    }
}

// ---------- main: one wave per batch row; gather ONLY mask!=0 rows ----------
// Depth-4 branch-free pipeline (act[] padded with row-0 entries -> L2 hits),
// score reduce entirely on the VALU via DPP (no DS-pipe latency in the loop).
__global__ __launch_bounds__(256, 8) void attn_kernel(
    const float* __restrict__ hist, const int* __restrict__ mask,
    const float* __restrict__ target, const float* __restrict__ MP,
    float* __restrict__ out)
{
    __shared__ int   act[4][224];      // active row indices + 19 pad entries
    __shared__ float c_lds[4][D];

    const int tid  = threadIdx.x;
    const int wave = tid >> 6, lane = tid & 63;
    const int b    = blockIdx.x * 4 + wave;
    const float* __restrict__ hb = hist + (size_t)b * (L * D);
    const int lr = lane >> 4;

    const float t = target[b * D + lane];

    // ---- compact active rows: lane l<50 owns mask rows 4l..4l+3 ----
    i32x4 mv = { 0, 0, 0, 0 };
    if (lane < 50) mv = *(const i32x4*)(mask + b * L + lane * 4);
    const unsigned long long below = (1ull << lane) - 1ull;
    int base = 0;
    #pragma unroll
    for (int k = 0; k < 4; ++k) {
        int mk = (k == 0) ? mv.x : (k == 1) ? mv.y : (k == 2) ? mv.z : mv.w;
        bool a_ = (lane < 50) && (mk != 0);
        unsigned long long bm = __ballot(a_);
        if (a_) act[wave][base + __popcll(bm & below)] = lane * 4 + k;
        base += __popcll(bm);
    }
    const int nA = base;
    if (lane < 20) act[wave][nA + lane] = 0;   // pads (weighted 0 later)
    const int nIt = (nA + 3) >> 2;

    const float* hbl = hb + (lane & 15) * 4;
    #define LOADROW(i) __builtin_nontemporal_load( \
        (const f32x4*)(hbl + act[wave][(i) * 4 + lr] * D))

    // depth-4 prefetch, branch-free (pads hit row 0 -> L2)
    f32x4 rA = LOADROW(0), rB = LOADROW(1), rC = LOADROW(2), rD = LOADROW(3);

    // ---- q~[lane] = INV_SCALE * sum_i t_i * M[i][lane]  (MP L1-resident) ----
    float qacc = 0.f;
    #pragma unroll 8
    for (int i = 0; i < D; ++i)
        qacc = fmaf(__shfl(t, i), MP[i * D + lane], qacc);
    qacc *= INV_SCALE;
    const int qb = (lane & 15) * 4;
    f32x4 q;
    q.x = __shfl(qacc, qb + 0);
    q.y = __shfl(qacc, qb + 1);
    q.z = __shfl(qacc, qb + 2);
    q.w = __shfl(qacc, qb + 3);

    // ---- main gather loop: 4 rows/iter, DPP 16-lane reduce, depth-4 ----
    f32x4 acc = { 0.f, 0.f, 0.f, 0.f };
    for (int i = 0; i < nIt; ++i) {
        f32x4 N = LOADROW(i + 4);
        float s = rA.x * q.x + rA.y * q.y + rA.z * q.z + rA.w * q.w;
        s = dpp_add<0xB1>(s);      // xor1 (quad_perm 1,0,3,2)
        s = dpp_add<0x4E>(s);      // xor2 (quad_perm 2,3,0,1)
        s = dpp_add<0x141>(s);     // row_half_mirror == xor4 here
        s = dpp_add<0x140>(s);     // row_mirror      == xor8 here
        float aw = (i * 4 + lr < nA) ? fmaxf(s, 0.f) : 0.f;
        acc += rA * aw;
        rA = rB; rB = rC; rC = rD; rD = N;
    }
    #undef LOADROW

    // reduce acc across the 4 row-groups (lanes xor 16, 32) — once per wave
    acc.x += __shfl_xor(acc.x, 16); acc.x += __shfl_xor(acc.x, 32);
    acc.y += __shfl_xor(acc.y, 16); acc.y += __shfl_xor(acc.y, 32);
    acc.z += __shfl_xor(acc.z, 16); acc.z += __shfl_xor(acc.z, 32);
    acc.w += __shfl_xor(acc.w, 16); acc.w += __shfl_xor(acc.w, 32);

    if (lane < 16) *(f32x4*)&c_lds[wave][lane * 4] = acc;
    // same-wave LDS RAW: ordered via lgkmcnt, no barrier needed

    // ---- epilogue: out[b][lane] = t + sum_i c[i] * P[i][lane] ----
    float o = t;
    const float* __restrict__ P = MP + 4096;
    #pragma unroll 8
    for (int i = 0; i < D; ++i)
        o = fmaf(c_lds[wave][i], P[i * D + lane], o);
    out[b * D + lane] = o;
}

extern "C" void kernel_launch(void* const* d_in, const int* in_sizes, int n_in,
                              void* d_out, int out_size, void* d_ws, size_t ws_size,
                              hipStream_t stream) {
    const float* target = (const float*)d_in[0];
    const float* hist   = (const float*)d_in[1];
    const int*   mask   = (const int*)d_in[2];
    const float* Wq     = (const float*)d_in[3];
    const float* Wk     = (const float*)d_in[4];
    const float* Wv     = (const float*)d_in[5];
    const float* Wo     = (const float*)d_in[6];
    float* outp = (float*)d_out;
    float* MP   = (float*)d_ws;                 // 8192 floats: M, then P

    prep_kernel<<<32, 256, 0, stream>>>(Wq, Wk, Wv, Wo, MP);
    attn_kernel<<<8192 / 4, 256, 0, stream>>>(hist, mask, target, MP, outp);
}

// Round 9
// 50.730 us; speedup vs baseline: 3.2589x; 1.0014x over previous
//
#include <hip/hip_runtime.h>

#define L 200
#define D 64
#define DA 128
#define INV_SCALE 0.088388347648318440550f  // 1/sqrt(128)

typedef float f32x4 __attribute__((ext_vector_type(4)));
typedef int   i32x4 __attribute__((ext_vector_type(4)));

// DPP-based add: x + dpp_perm(x). CTRL: 0xB1 = quad_perm(xor1),
// 0x4E = quad_perm(xor2), 0x141 = row_half_mirror (== xor4 once quads are
// uniform), 0x140 = row_mirror (== xor8 once 8-groups are uniform).
template <int CTRL>
__device__ __forceinline__ float dpp_add(float x) {
    int xi = __builtin_bit_cast(int, x);
    int yi = __builtin_amdgcn_update_dpp(xi, xi, CTRL, 0xF, 0xF, false);
    return x + __builtin_bit_cast(float, yi);
}

// ---------- prep: M = W_q @ W_k^T (64x64), P = W_v @ W_o (64x64) ----------
__global__ __launch_bounds__(256) void prep_kernel(
    const float* __restrict__ Wq, const float* __restrict__ Wk,
    const float* __restrict__ Wv, const float* __restrict__ Wo,
    float* __restrict__ MP)
{
    int gid = blockIdx.x * 256 + threadIdx.x;
    if (gid < 4096) {
        int i = gid >> 6, j = gid & 63;
        float s = 0.f;
        #pragma unroll 8
        for (int a = 0; a < DA; ++a) s += Wq[i * DA + a] * Wk[j * DA + a];
        MP[gid] = s;                       // M[i][j]
    } else if (gid < 8192) {
        int g = gid - 4096;
        int i = g >> 6, j = g & 63;
        float s = 0.f;
        #pragma unroll 8
        for (int a = 0; a < DA; ++a) s += Wv[i * DA + a] * Wo[a * D + j];
        MP[gid] = s;                       // P[i][j]
    }
}

// ---------- main: one wave per batch row; gather ONLY mask!=0 rows ----------
// Depth-4 branch-free pipeline (act[] padded with row-0 entries -> L2 hits),
// score reduce entirely on the VALU via DPP (no DS-pipe latency in the loop).
__global__ __launch_bounds__(256, 8) void attn_kernel(
    const float* __restrict__ hist, const int* __restrict__ mask,
    const float* __restrict__ target, const float* __restrict__ MP,
    float* __restrict__ out)
{
    __shared__ int   act[4][224];      // active row indices + 19 pad entries
    __shared__ float c_lds[4][D];

    const int tid  = threadIdx.x;
    const int wave = tid >> 6, lane = tid & 63;
    const int b    = blockIdx.x * 4 + wave;
    const float* __restrict__ hb = hist + (size_t)b * (L * D);
    const int lr = lane >> 4;

    const float t = target[b * D + lane];

    // ---- compact active rows: lane l<50 owns mask rows 4l..4l+3 ----
    i32x4 mv = { 0, 0, 0, 0 };
    if (lane < 50) mv = *(const i32x4*)(mask + b * L + lane * 4);
    const unsigned long long below = (1ull << lane) - 1ull;
    int base = 0;
    #pragma unroll
    for (int k = 0; k < 4; ++k) {
        int mk = (k == 0) ? mv.x : (k == 1) ? mv.y : (k == 2) ? mv.z : mv.w;
        bool a_ = (lane < 50) && (mk != 0);
        unsigned long long bm = __ballot(a_);
        if (a_) act[wave][base + __popcll(bm & below)] = lane * 4 + k;
        base += __popcll(bm);
    }
    const int nA = base;
    if (lane < 20) act[wave][nA + lane] = 0;   // pads (weighted 0 later)
    const int nIt = (nA + 3) >> 2;

    const float* hbl = hb + (lane & 15) * 4;
    #define LOADROW(i) __builtin_nontemporal_load( \
        (const f32x4*)(hbl + act[wave][(i) * 4 + lr] * D))

    // depth-4 prefetch, branch-free (pads hit row 0 -> L2)
    f32x4 rA = LOADROW(0), rB = LOADROW(1), rC = LOADROW(2), rD = LOADROW(3);

    // ---- q~[lane] = INV_SCALE * sum_i t_i * M[i][lane]  (MP L1-resident) ----
    float qacc = 0.f;
    #pragma unroll 8
    for (int i = 0; i < D; ++i)
        qacc = fmaf(__shfl(t, i), MP[i * D + lane], qacc);
    qacc *= INV_SCALE;
    const int qb = (lane & 15) * 4;
    f32x4 q;
    q.x = __shfl(qacc, qb + 0);
    q.y = __shfl(qacc, qb + 1);
    q.z = __shfl(qacc, qb + 2);
    q.w = __shfl(qacc, qb + 3);

    // ---- main gather loop: 4 rows/iter, DPP 16-lane reduce, depth-4 ----
    f32x4 acc = { 0.f, 0.f, 0.f, 0.f };
    for (int i = 0; i < nIt; ++i) {
        f32x4 N = LOADROW(i + 4);
        float s = rA.x * q.x + rA.y * q.y + rA.z * q.z + rA.w * q.w;
        s = dpp_add<0xB1>(s);      // xor1 (quad_perm 1,0,3,2)
        s = dpp_add<0x4E>(s);      // xor2 (quad_perm 2,3,0,1)
        s = dpp_add<0x141>(s);     // row_half_mirror == xor4 here
        s = dpp_add<0x140>(s);     // row_mirror      == xor8 here
        float aw = (i * 4 + lr < nA) ? fmaxf(s, 0.f) : 0.f;
        acc += rA * aw;
        rA = rB; rB = rC; rC = rD; rD = N;
    }
    #undef LOADROW

    // reduce acc across the 4 row-groups (lanes xor 16, 32) — once per wave
    acc.x += __shfl_xor(acc.x, 16); acc.x += __shfl_xor(acc.x, 32);
    acc.y += __shfl_xor(acc.y, 16); acc.y += __shfl_xor(acc.y, 32);
    acc.z += __shfl_xor(acc.z, 16); acc.z += __shfl_xor(acc.z, 32);
    acc.w += __shfl_xor(acc.w, 16); acc.w += __shfl_xor(acc.w, 32);

    if (lane < 16) *(f32x4*)&c_lds[wave][lane * 4] = acc;
    // same-wave LDS RAW: ordered via lgkmcnt, no barrier needed

    // ---- epilogue: out[b][lane] = t + sum_i c[i] * P[i][lane] ----
    float o = t;
    const float* __restrict__ P = MP + 4096;
    #pragma unroll 8
    for (int i = 0; i < D; ++i)
        o = fmaf(c_lds[wave][i], P[i * D + lane], o);
    out[b * D + lane] = o;
}

extern "C" void kernel_launch(void* const* d_in, const int* in_sizes, int n_in,
                              void* d_out, int out_size, void* d_ws, size_t ws_size,
                              hipStream_t stream) {
    const float* target = (const float*)d_in[0];
    const float* hist   = (const float*)d_in[1];
    const int*   mask   = (const int*)d_in[2];
    const float* Wq     = (const float*)d_in[3];
    const float* Wk     = (const float*)d_in[4];
    const float* Wv     = (const float*)d_in[5];
    const float* Wo     = (const float*)d_in[6];
    float* outp = (float*)d_out;
    float* MP   = (float*)d_ws;                 // 8192 floats: M, then P

    prep_kernel<<<32, 256, 0, stream>>>(Wq, Wk, Wv, Wo, MP);
    attn_kernel<<<8192 / 4, 256, 0, stream>>>(hist, mask, target, MP, outp);
}